// Round 8
// baseline (248.958 us; speedup 1.0000x reference)
//
#include <hip/hip_runtime.h>
#include <hip/hip_bf16.h>
#include <math.h>

#define LN_EPS 1e-5f
// Fixed-capacity dst-buckets: bucket = 64 dest nodes, CAP 2048 slots (expected fill ~1024,
// max ~1200 + <=448 pad-to-8; inputs are deterministic). pk packs (dstLocal<<20)|src, N <= 2^20.
// LESSON (r5): no LDS f32 atomics in per-edge loops. Wave-per-node register agg is right.
// LESSON (r6): agg is latency-bound: pad degree to x8 (dummy row N), lane-coop prefetch +
// readlane scalar-base gathers. ~65us floor at 70% occupancy.
// LESSON (r8): NO GLOBAL ATOMICS in per-edge loops; block-level reservation atomics OK.
// LESSON (r9): fuse independent partition||gemm in ONE dispatch; agg folds dinv[src] per edge.
// LESSON (r11): csr merged INTO agg (bucket fits LDS) kills the srcidx HBM round-trip.
// LESSON (r12): merged agg at 782 blocks = 3 blk/CU -> occupancy 26.5%, agg 65->80us. The
// gather loop needs ~6+ blk/CU: bucket 128->64 nodes (1563 blocks). Partition scatter write-
// amplification ~ NPBLK x NBUCK lines: drop LDS edge buffer (re-read ei, L2-hot) -> 128
// partition blocks, 12.8KB LDS, half the line touches.
// (r13): identical resubmit of r12's kernel -- r12 bench was an infra flake (container failed
// twice, no compile/correctness signal; source audited clean: bounded loops, guarded writes).
#define CAP 2048
#define CAPSH 11
#define SIDXSZ (CAP + 448)        // padded total <= cntb + 64*7
#define NPBLK 128
#define MAXBUCK 1600

typedef __attribute__((ext_vector_type(8))) short short8;
typedef __attribute__((ext_vector_type(4))) float floatx4;

// ---- tiny init: W fp32[k][n] -> bf16 Wt[n][k]; zero bucketCnt, dummy g-row, dinv[N] ----
__global__ __launch_bounds__(256) void k_init(const float* __restrict__ W, __hip_bfloat16* __restrict__ Wt,
                                              int* __restrict__ bucketCnt, unsigned* __restrict__ gdummy,
                                              float* __restrict__ dinv, int N) {
    int t = threadIdx.x;
    int i = blockIdx.x * 256 + t;               // 64 blocks x 256 = 16384
    int n = i >> 7, k = i & 127;
    Wt[i] = __float2bfloat16(W[k * 128 + n]);
    if (blockIdx.x == 0) {
        for (int j = t; j < MAXBUCK; j += 256) bucketCnt[j] = 0;
        if (t < 64) gdummy[t] = 0;              // g row N = 0 (pad-edge target)
        if (t == 0) dinv[N] = 0.f;              // pad-edge weight = 0 (NaN guard)
    }
}

// ---- FUSED: blocks [0,NPBLK) partition edges; blocks [NPBLK,..) MFMA GEMM (independent) ----
// partition: two passes over the chunk (hist, then rank+scatter re-reading ei from L2);
// no LDS edge buffer -> 12.8KB LDS -> big chunks (few blocks) -> fewer scatter line touches.
// gemm: g = bf16(x @ W) UNSCALED -- B tile LDS-staged+swizzled, A fragments direct from global.
__global__ __launch_bounds__(256) void k_part_gemm(const int* __restrict__ ei, int* __restrict__ bucketCnt,
                                                   unsigned* __restrict__ pk, int E, int chunk,
                                                   const float* __restrict__ x, const __hip_bfloat16* __restrict__ Wt,
                                                   __hip_bfloat16* __restrict__ g, int N) {
    __shared__ union {
        struct { int h[MAXBUCK]; int base[MAXBUCK]; } part;   // 12.8 KB
        unsigned short sB[128 * 128];                          // 32 KB
    } u;
    if ((int)blockIdx.x < NPBLK) {
        // ---------------- partition ----------------
        int t = threadIdx.x;
        for (int i = t; i < MAXBUCK; i += 256) u.part.h[i] = 0;
        int e0 = blockIdx.x * chunk;
        int e1 = min(e0 + chunk, E);
        __syncthreads();
        for (int i = e0 + t; i < e1; i += 256)            // pass 1: histogram (cols only)
            atomicAdd(&u.part.h[ei[E + i] >> 6], 1);
        __syncthreads();
        for (int i = t; i < MAXBUCK; i += 256) {
            if (u.part.h[i] > 0) {
                u.part.base[i] = atomicAdd(&bucketCnt[i], u.part.h[i]);  // block-level reservation
                u.part.h[i] = 0;                                         // reuse as local rank cursor
            }
        }
        __syncthreads();
        for (int i = e0 + t; i < e1; i += 256) {          // pass 2: rank + scatter (re-read, L2-hot)
            int col = ei[E + i];
            int src = ei[i];
            int b = col >> 6;
            int r = u.part.base[b] + atomicAdd(&u.part.h[b], 1);
            if (r < CAP)                                  // overflow guard (never hit; no corruption)
                pk[((unsigned)b << CAPSH) + r] = ((unsigned)(col & 63) << 20) | (unsigned)src;
        }
    } else {
        // ---------------- gemm ----------------
        int tid = threadIdx.x;
        int row0 = ((int)blockIdx.x - NPBLK) * 128;
#pragma unroll
        for (int i = 0; i < 8; ++i) {                // stage B only: 16384 shorts / 256 thr
            int idx = tid + i * 256;                 // 0..2047
            int row = idx >> 4;
            int gr = idx & 15;
            int grs = gr ^ (row & 15);
            *(short8*)(&u.sB[row * 128 + grs * 8]) = *(const short8*)(Wt + (size_t)row * 128 + gr * 8);
        }
        __syncthreads();
        int lane = tid & 63;
        int wv = tid >> 6;
        int m = lane & 15;
        int q = lane >> 4;
        floatx4 acc[2][8];
#pragma unroll
        for (int mt = 0; mt < 2; ++mt)
#pragma unroll
            for (int nt = 0; nt < 8; ++nt) acc[mt][nt] = (floatx4){0.f, 0.f, 0.f, 0.f};
#pragma unroll
        for (int kc = 0; kc < 4; ++kc) {
            int gg = kc * 4 + q;
            short8 afrag[2], bfrag[8];
#pragma unroll
            for (int mt = 0; mt < 2; ++mt) {         // A direct from global (no reuse in block)
                int arow = min(row0 + wv * 32 + mt * 16 + m, N - 1);
                const float* xp = x + (size_t)arow * 128 + gg * 8;
                float4 xa = *(const float4*)xp;
                float4 xb = *(const float4*)(xp + 4);
                union { short8 s; __hip_bfloat16 h[8]; } a;
                a.h[0] = __float2bfloat16(xa.x); a.h[1] = __float2bfloat16(xa.y);
                a.h[2] = __float2bfloat16(xa.z); a.h[3] = __float2bfloat16(xa.w);
                a.h[4] = __float2bfloat16(xb.x); a.h[5] = __float2bfloat16(xb.y);
                a.h[6] = __float2bfloat16(xb.z); a.h[7] = __float2bfloat16(xb.w);
                afrag[mt] = a.s;
            }
#pragma unroll
            for (int nt = 0; nt < 8; ++nt) {
                int n = nt * 16 + m;
                bfrag[nt] = *(const short8*)(&u.sB[n * 128 + (gg ^ (n & 15)) * 8]);
            }
#pragma unroll
            for (int mt = 0; mt < 2; ++mt)
#pragma unroll
                for (int nt = 0; nt < 8; ++nt)
                    acc[mt][nt] = __builtin_amdgcn_mfma_f32_16x16x32_bf16(afrag[mt], bfrag[nt], acc[mt][nt], 0, 0, 0);
        }
#pragma unroll
        for (int mt = 0; mt < 2; ++mt) {
#pragma unroll
            for (int i = 0; i < 4; ++i) {
                int row = row0 + wv * 32 + mt * 16 + q * 4 + i;
                if (row < N) {
                    __hip_bfloat16* gp = g + (size_t)row * 128;
#pragma unroll
                    for (int nt = 0; nt < 8; ++nt)
                        gp[nt * 16 + m] = __float2bfloat16(acc[mt][nt][i]);
                }
            }
        }
    }
}

// ---- per-node degree + dinv from pk (one block per bucket; LDS histogram) ----
__global__ __launch_bounds__(256) void k_deg(const unsigned* __restrict__ pk, const int* __restrict__ bucketCnt,
                                             int* __restrict__ cnt, float* __restrict__ dinv, int N) {
    __shared__ int lc[64];
    int b = blockIdx.x;
    int t = threadIdx.x;
    if (t < 64) lc[t] = 0;
    __syncthreads();
    int ofs = b << CAPSH;
    int cntb = min(bucketCnt[b], CAP);
    for (int e = t; e < cntb; e += 256)
        atomicAdd(&lc[pk[ofs + e] >> 20], 1);
    __syncthreads();
    int node = (b << 6) + t;
    if (t < 64 && node < N) {
        cnt[node] = lc[t];
        dinv[node] = rsqrtf((float)(lc[t] + 1));    // +1 self-loop
    }
}

// ---------- MERGED: bucket->LDS-CSR + aggregate + bias + LayerNorm + ReLU ----------
// Block = one 64-node bucket (1563 blocks, ~6/CU -> occupancy back). Phase 1: scan padded
// cnt -> per-node LDS ranges (+pad with N). Phase 2: scatter bucket's pk into LDS sidx.
// Phase 3: wave-per-node gather (indices from LDS), dinv[src] weight via readlane FMA, LN+ReLU.
#define RLF(V, I) __int_as_float(__builtin_amdgcn_readlane(__float_as_int(V), (I)))

#define LOAD8(P, B) \
    unsigned P##0 = g1[((size_t)(unsigned)__builtin_amdgcn_readlane(myidx, (B) + 0)) * 64u + lane]; \
    unsigned P##1 = g1[((size_t)(unsigned)__builtin_amdgcn_readlane(myidx, (B) + 1)) * 64u + lane]; \
    unsigned P##2 = g1[((size_t)(unsigned)__builtin_amdgcn_readlane(myidx, (B) + 2)) * 64u + lane]; \
    unsigned P##3 = g1[((size_t)(unsigned)__builtin_amdgcn_readlane(myidx, (B) + 3)) * 64u + lane]; \
    unsigned P##4 = g1[((size_t)(unsigned)__builtin_amdgcn_readlane(myidx, (B) + 4)) * 64u + lane]; \
    unsigned P##5 = g1[((size_t)(unsigned)__builtin_amdgcn_readlane(myidx, (B) + 5)) * 64u + lane]; \
    unsigned P##6 = g1[((size_t)(unsigned)__builtin_amdgcn_readlane(myidx, (B) + 6)) * 64u + lane]; \
    unsigned P##7 = g1[((size_t)(unsigned)__builtin_amdgcn_readlane(myidx, (B) + 7)) * 64u + lane];

#define WACC8(P, B) { \
    float w0 = RLF(dlv, (B) + 0), w1 = RLF(dlv, (B) + 1), w2 = RLF(dlv, (B) + 2), w3 = RLF(dlv, (B) + 3); \
    float w4 = RLF(dlv, (B) + 4), w5 = RLF(dlv, (B) + 5), w6 = RLF(dlv, (B) + 6), w7 = RLF(dlv, (B) + 7); \
    ax += ((__uint_as_float(P##0 << 16) * w0 + __uint_as_float(P##1 << 16) * w1) + \
           (__uint_as_float(P##2 << 16) * w2 + __uint_as_float(P##3 << 16) * w3)) + \
          ((__uint_as_float(P##4 << 16) * w4 + __uint_as_float(P##5 << 16) * w5) + \
           (__uint_as_float(P##6 << 16) * w6 + __uint_as_float(P##7 << 16) * w7)); \
    ay += ((__uint_as_float(P##0 & 0xFFFF0000u) * w0 + __uint_as_float(P##1 & 0xFFFF0000u) * w1) + \
           (__uint_as_float(P##2 & 0xFFFF0000u) * w2 + __uint_as_float(P##3 & 0xFFFF0000u) * w3)) + \
          ((__uint_as_float(P##4 & 0xFFFF0000u) * w4 + __uint_as_float(P##5 & 0xFFFF0000u) * w5) + \
           (__uint_as_float(P##6 & 0xFFFF0000u) * w6 + __uint_as_float(P##7 & 0xFFFF0000u) * w7)); }

__global__ __launch_bounds__(256) void k_agg_ln(const __hip_bfloat16* __restrict__ g, const unsigned* __restrict__ pk,
                                                const int* __restrict__ bucketCnt, const int* __restrict__ cnt,
                                                const float* __restrict__ dinv, const float* __restrict__ bias,
                                                const float* __restrict__ gamma, const float* __restrict__ beta,
                                                float* __restrict__ out, int N) {
    __shared__ int sidx[SIDXSZ];    // ~10 KB: bucket's node-grouped src indices
    __shared__ int sscan[256];
    __shared__ int lofs[64];
    __shared__ int pvs[64];
    __shared__ int lcnt[64];
    int b = blockIdx.x;
    int t = threadIdx.x;
    int ofs = b << CAPSH;
    int cntb = min(bucketCnt[b], CAP);
    // ---- phase 1: scan padded per-node counts ----
    int nd = (b << 6) + t;
    int v = (t < 64 && nd < N) ? cnt[nd] : 0;
    int pv = (v + 7) & ~7;          // pad to x8 (t>=64 contributes 0)
    sscan[t] = pv;
    __syncthreads();
    int val = pv;
    for (int off = 1; off < 256; off <<= 1) {
        int add = (t >= off) ? sscan[t - off] : 0;
        __syncthreads();
        val += add;
        sscan[t] = val;
        __syncthreads();
    }
    if (t < 64) {
        int base = val - pv;
        lofs[t] = base;
        pvs[t] = pv;
        lcnt[t] = 0;
        for (int i = v; i < pv; ++i) {          // pad slots -> dummy row N (dinv[N]=0)
            int sl = base + i;
            if (sl < SIDXSZ) sidx[sl] = N;
        }
    }
    __syncthreads();
    // ---- phase 2: scatter pk into LDS sidx ----
    for (int e = t; e < cntb; e += 256) {
        unsigned u = pk[ofs + e];
        int d = u >> 20;
        int r = atomicAdd(&lcnt[d], 1);
        int sl = lofs[d] + r;
        if (sl < SIDXSZ) sidx[sl] = (int)(u & 0xFFFFFu);
    }
    __syncthreads();
    // ---- phase 3: wave-per-node aggregate + LN + ReLU ----
    int lane = t & 63;
    int wv = t >> 6;
    const unsigned* g1 = (const unsigned*)g;    // u32 = channels {2*lane, 2*lane+1}
    float2 bi = ((const float2*)bias)[lane];
    float2 ga = ((const float2*)gamma)[lane];
    float2 be = ((const float2*)beta)[lane];
    for (int ii = 0; ii < 16; ++ii) {
        int nl = wv * 16 + ii;
        int node = (b << 6) + nl;
        if (node >= N) break;                   // wave-uniform
        int startL = lofs[nl];
        int endL = startL + pvs[nl];
        float di = dinv[node];
        unsigned sv = g1[(size_t)node * 64 + lane];
        float ax = __uint_as_float(sv << 16) * di;          // self-loop: dinv[i]*h[i]
        float ay = __uint_as_float(sv & 0xFFFF0000u) * di;
        for (int eb = startL; eb < endL; eb += 64) {
            int myidx = (eb + lane < endL) ? sidx[eb + lane] : N;   // LDS, guarded
            float dlv = dinv[myidx];            // per-edge weight (L2-hot table; dinv[N]=0)
            int nb = min(64, endL - eb);        // multiple of 8
            if (nb >= 24) {                     // issue 24 before first use
                LOAD8(pa, 0)
                LOAD8(pb, 8)
                LOAD8(pc, 16)
                WACC8(pa, 0)
                WACC8(pb, 8)
                WACC8(pc, 16)
                for (int j = 24; j + 8 <= nb; j += 8) {   // deg>24 tail (~2% of nodes)
                    LOAD8(pd, j)
                    WACC8(pd, j)
                }
            } else if (nb == 16) {
                LOAD8(pe, 0)
                LOAD8(pf, 8)
                WACC8(pe, 0)
                WACC8(pf, 8)
            } else {
                LOAD8(pg, 0)
                WACC8(pg, 0)
            }
        }
        float vx = ax * di + bi.x;
        float vy = ay * di + bi.y;
        float sum = vx + vy, sq = vx * vx + vy * vy;
#pragma unroll
        for (int off = 32; off > 0; off >>= 1) {
            sum += __shfl_xor(sum, off, 64);
            sq += __shfl_xor(sq, off, 64);
        }
        float mu = sum * (1.0f / 128.0f);
        float var = sq * (1.0f / 128.0f) - mu * mu;
        float rstd = rsqrtf(var + LN_EPS);
        float o0 = fmaxf((vx - mu) * rstd * ga.x + be.x, 0.f);
        float o1 = fmaxf((vy - mu) * rstd * ga.y + be.y, 0.f);
        ((float2*)out)[(size_t)node * 64 + lane] = make_float2(o0, o1);
    }
}

extern "C" void kernel_launch(void* const* d_in, const int* in_sizes, int n_in,
                              void* d_out, int out_size, void* d_ws, size_t ws_size,
                              hipStream_t stream) {
    const float* x = (const float*)d_in[0];
    const int* ei = (const int*)d_in[1];
    const float* W = (const float*)d_in[2];
    const float* bias = (const float*)d_in[3];
    const float* gamma = (const float*)d_in[4];
    const float* beta = (const float*)d_in[5];
    float* out = (float*)d_out;

    int N = in_sizes[0] / 128;
    int E = in_sizes[1] / 2;
    int NBUCK = (N + 63) / 64;                   // 64-node buckets (1563)

    char* p = (char*)d_ws;
    auto alloc = [&](size_t bytes) {
        char* r = p;
        p += (bytes + 255) & ~(size_t)255;
        return r;
    };
    int* bucketCnt = (int*)alloc(MAXBUCK * 4);
    int* cnt = (int*)alloc((size_t)N * 4);
    float* dinv = (float*)alloc((size_t)(N + 1) * 4);            // +1: dinv[N]=0 pad weight
    __hip_bfloat16* Wt = (__hip_bfloat16*)alloc(128 * 128 * 2);
    unsigned* pk = (unsigned*)alloc((size_t)NBUCK * CAP * 4);    // 12.8MB (ws: agg reads pk while writing d_out)
    __hip_bfloat16* gbuf = (__hip_bfloat16*)alloc((size_t)(N + 1) * 128 * 2);  // +1 dummy zero row

    int chunk = (E + NPBLK - 1) / NPBLK;         // 12500 edges per partition block
    int GB = (N + 127) / 128;

    k_init<<<64, 256, 0, stream>>>(W, Wt, bucketCnt, (unsigned*)(gbuf + (size_t)N * 128), dinv, N);
    k_part_gemm<<<NPBLK + GB, 256, 0, stream>>>(ei, bucketCnt, pk, E, chunk, x, Wt, gbuf, N);
    k_deg<<<NBUCK, 256, 0, stream>>>(pk, bucketCnt, cnt, dinv, N);
    k_agg_ln<<<NBUCK, 256, 0, stream>>>(gbuf, pk, bucketCnt, cnt, dinv, bias, gamma, beta, out, N);
}

// Round 9
// 212.650 us; speedup vs baseline: 1.1707x; 1.1707x over previous
//
#include <hip/hip_runtime.h>
#include <hip/hip_bf16.h>
#include <math.h>

#define LN_EPS 1e-5f
// Fixed-capacity dst-buckets: bucket = 128 dest nodes, CAP 4096 slots (expected fill ~2050;
// deterministic inputs). pk packs (dstLocal<<20)|src, dstLocal 7 bits, N <= 2^20.
// LESSON (r5): no LDS f32 atomics in per-edge loops. Wave-per-node register agg is right.
// LESSON (r6): agg is latency-bound: pad degree to x8 (dummy row N), lane-coop prefetch +
// readlane scalar-base gathers. ~65us floor at 70% occupancy.
// LESSON (r8): NO GLOBAL ATOMICS in per-edge loops; block-level reservation atomics OK.
// LESSON (r9): fuse independent partition||gemm in ONE dispatch; agg folds dinv[src] per edge.
// LESSON (r11): csr merged INTO agg (bucket fits LDS) kills the srcidx HBM round-trip.
// LESSON (r12): merged agg needs >=6 blk/CU -> 64-node agg granularity (half-buckets).
// LESSON (r14): partition needs MANY medium blocks co-resident with gemm, NOT few huge ones:
// 128x12500-edge blocks -> occupancy 10%, 84us (half the CUs idle, serial atomic chains).
// LDS edge buffering + 576 blocks is the proven shape. Write-amp is the cheaper evil.
#define CAP 4096
#define CAPSH 12
#define SIDXSZ 2496               // half-bucket padded total (~1100 typ; guarded)
#define NPBLK 576
#define ECHUNK 2816
#define MAXBUCK 800

typedef __attribute__((ext_vector_type(8))) short short8;
typedef __attribute__((ext_vector_type(4))) float floatx4;

// ---- tiny init: W fp32[k][n] -> bf16 Wt[n][k]; zero bucketCnt, dummy g-row, dinv[N] ----
__global__ __launch_bounds__(256) void k_init(const float* __restrict__ W, __hip_bfloat16* __restrict__ Wt,
                                              int* __restrict__ bucketCnt, unsigned* __restrict__ gdummy,
                                              float* __restrict__ dinv, int N) {
    int t = threadIdx.x;
    int i = blockIdx.x * 256 + t;               // 64 blocks x 256 = 16384
    int n = i >> 7, k = i & 127;
    Wt[i] = __float2bfloat16(W[k * 128 + n]);
    if (blockIdx.x == 0) {
        for (int j = t; j < MAXBUCK; j += 256) bucketCnt[j] = 0;
        if (t < 64) gdummy[t] = 0;              // g row N = 0 (pad-edge target)
        if (t == 0) dinv[N] = 0.f;              // pad-edge weight = 0 (NaN guard)
    }
}

// ---- FUSED: blocks [0,NPBLK) partition edges; blocks [NPBLK,..) MFMA GEMM (independent) ----
// partition (r5-proven): single pass over ei, LDS edge buffer, block-level reservations.
// gemm: g = bf16(x @ W) UNSCALED -- B tile LDS-staged+swizzled, A fragments direct from global.
__global__ __launch_bounds__(256) void k_part_gemm(const int* __restrict__ ei, int* __restrict__ bucketCnt,
                                                   unsigned* __restrict__ pk, int E, int chunk,
                                                   const float* __restrict__ x, const __hip_bfloat16* __restrict__ Wt,
                                                   __hip_bfloat16* __restrict__ g, int N) {
    __shared__ union {
        struct { int ecol[ECHUNK]; int esrc[ECHUNK]; int h[MAXBUCK]; int base[MAXBUCK]; } part;  // 28.3 KB
        unsigned short sB[128 * 128];                                                            // 32 KB
    } u;
    if ((int)blockIdx.x < NPBLK) {
        // ---------------- partition ----------------
        int t = threadIdx.x;
        for (int i = t; i < MAXBUCK; i += 256) u.part.h[i] = 0;
        int e0 = blockIdx.x * chunk;
        int e1 = min(e0 + chunk, E);
        int n = e1 - e0;
        __syncthreads();
        for (int i = t; i < n; i += 256) {
            int col = ei[E + e0 + i];
            u.part.ecol[i] = col;
            u.part.esrc[i] = ei[e0 + i];
            atomicAdd(&u.part.h[col >> 7], 1);
        }
        __syncthreads();
        for (int i = t; i < MAXBUCK; i += 256) {
            if (u.part.h[i] > 0) {
                u.part.base[i] = atomicAdd(&bucketCnt[i], u.part.h[i]);  // block-level reservation
                u.part.h[i] = 0;                                         // reuse as local rank cursor
            }
        }
        __syncthreads();
        for (int i = t; i < n; i += 256) {
            int col = u.part.ecol[i];
            int b = col >> 7;
            int r = u.part.base[b] + atomicAdd(&u.part.h[b], 1);
            if (r < CAP)                                    // overflow guard (never hit; no corruption)
                pk[((unsigned)b << CAPSH) + r] = ((unsigned)(col & 127) << 20) | (unsigned)u.part.esrc[i];
        }
    } else {
        // ---------------- gemm ----------------
        int tid = threadIdx.x;
        int row0 = ((int)blockIdx.x - NPBLK) * 128;
#pragma unroll
        for (int i = 0; i < 8; ++i) {                // stage B only: 16384 shorts / 256 thr
            int idx = tid + i * 256;                 // 0..2047
            int row = idx >> 4;
            int gr = idx & 15;
            int grs = gr ^ (row & 15);
            *(short8*)(&u.sB[row * 128 + grs * 8]) = *(const short8*)(Wt + (size_t)row * 128 + gr * 8);
        }
        __syncthreads();
        int lane = tid & 63;
        int wv = tid >> 6;
        int m = lane & 15;
        int q = lane >> 4;
        floatx4 acc[2][8];
#pragma unroll
        for (int mt = 0; mt < 2; ++mt)
#pragma unroll
            for (int nt = 0; nt < 8; ++nt) acc[mt][nt] = (floatx4){0.f, 0.f, 0.f, 0.f};
#pragma unroll
        for (int kc = 0; kc < 4; ++kc) {
            int gg = kc * 4 + q;
            short8 afrag[2], bfrag[8];
#pragma unroll
            for (int mt = 0; mt < 2; ++mt) {         // A direct from global (no reuse in block)
                int arow = min(row0 + wv * 32 + mt * 16 + m, N - 1);
                const float* xp = x + (size_t)arow * 128 + gg * 8;
                float4 xa = *(const float4*)xp;
                float4 xb = *(const float4*)(xp + 4);
                union { short8 s; __hip_bfloat16 h[8]; } a;
                a.h[0] = __float2bfloat16(xa.x); a.h[1] = __float2bfloat16(xa.y);
                a.h[2] = __float2bfloat16(xa.z); a.h[3] = __float2bfloat16(xa.w);
                a.h[4] = __float2bfloat16(xb.x); a.h[5] = __float2bfloat16(xb.y);
                a.h[6] = __float2bfloat16(xb.z); a.h[7] = __float2bfloat16(xb.w);
                afrag[mt] = a.s;
            }
#pragma unroll
            for (int nt = 0; nt < 8; ++nt) {
                int n = nt * 16 + m;
                bfrag[nt] = *(const short8*)(&u.sB[n * 128 + (gg ^ (n & 15)) * 8]);
            }
#pragma unroll
            for (int mt = 0; mt < 2; ++mt)
#pragma unroll
                for (int nt = 0; nt < 8; ++nt)
                    acc[mt][nt] = __builtin_amdgcn_mfma_f32_16x16x32_bf16(afrag[mt], bfrag[nt], acc[mt][nt], 0, 0, 0);
        }
#pragma unroll
        for (int mt = 0; mt < 2; ++mt) {
#pragma unroll
            for (int i = 0; i < 4; ++i) {
                int row = row0 + wv * 32 + mt * 16 + q * 4 + i;
                if (row < N) {
                    __hip_bfloat16* gp = g + (size_t)row * 128;
#pragma unroll
                    for (int nt = 0; nt < 8; ++nt)
                        gp[nt * 16 + m] = __float2bfloat16(acc[mt][nt][i]);
                }
            }
        }
    }
}

// ---- per-node degree + dinv from pk (one block per 128-node bucket; LDS histogram) ----
__global__ __launch_bounds__(256) void k_deg(const unsigned* __restrict__ pk, const int* __restrict__ bucketCnt,
                                             int* __restrict__ cnt, float* __restrict__ dinv, int N) {
    __shared__ int lc[128];
    int b = blockIdx.x;
    int t = threadIdx.x;
    if (t < 128) lc[t] = 0;
    __syncthreads();
    int ofs = b << CAPSH;
    int cntb = min(bucketCnt[b], CAP);
    for (int e = t; e < cntb; e += 256)
        atomicAdd(&lc[pk[ofs + e] >> 20], 1);
    __syncthreads();
    int node = (b << 7) + t;
    if (t < 128 && node < N) {
        cnt[node] = lc[t];
        dinv[node] = rsqrtf((float)(lc[t] + 1));    // +1 self-loop
    }
}

// ---------- MERGED: half-bucket LDS-CSR + aggregate + bias + LayerNorm + ReLU ----------
// Block = one 64-node HALF of a 128-bucket (1564 blocks, ~6/CU). Phase 1: scan padded cnt.
// Phase 2: scan bucket's pk, keep own half (d>>6==half), scatter into LDS sidx. Phase 3:
// wave-per-node gather (indices from LDS), dinv[src] weight via readlane FMA, LN+ReLU.
#define RLF(V, I) __int_as_float(__builtin_amdgcn_readlane(__float_as_int(V), (I)))

#define LOAD8(P, B) \
    unsigned P##0 = g1[((size_t)(unsigned)__builtin_amdgcn_readlane(myidx, (B) + 0)) * 64u + lane]; \
    unsigned P##1 = g1[((size_t)(unsigned)__builtin_amdgcn_readlane(myidx, (B) + 1)) * 64u + lane]; \
    unsigned P##2 = g1[((size_t)(unsigned)__builtin_amdgcn_readlane(myidx, (B) + 2)) * 64u + lane]; \
    unsigned P##3 = g1[((size_t)(unsigned)__builtin_amdgcn_readlane(myidx, (B) + 3)) * 64u + lane]; \
    unsigned P##4 = g1[((size_t)(unsigned)__builtin_amdgcn_readlane(myidx, (B) + 4)) * 64u + lane]; \
    unsigned P##5 = g1[((size_t)(unsigned)__builtin_amdgcn_readlane(myidx, (B) + 5)) * 64u + lane]; \
    unsigned P##6 = g1[((size_t)(unsigned)__builtin_amdgcn_readlane(myidx, (B) + 6)) * 64u + lane]; \
    unsigned P##7 = g1[((size_t)(unsigned)__builtin_amdgcn_readlane(myidx, (B) + 7)) * 64u + lane];

#define WACC8(P, B) { \
    float w0 = RLF(dlv, (B) + 0), w1 = RLF(dlv, (B) + 1), w2 = RLF(dlv, (B) + 2), w3 = RLF(dlv, (B) + 3); \
    float w4 = RLF(dlv, (B) + 4), w5 = RLF(dlv, (B) + 5), w6 = RLF(dlv, (B) + 6), w7 = RLF(dlv, (B) + 7); \
    ax += ((__uint_as_float(P##0 << 16) * w0 + __uint_as_float(P##1 << 16) * w1) + \
           (__uint_as_float(P##2 << 16) * w2 + __uint_as_float(P##3 << 16) * w3)) + \
          ((__uint_as_float(P##4 << 16) * w4 + __uint_as_float(P##5 << 16) * w5) + \
           (__uint_as_float(P##6 << 16) * w6 + __uint_as_float(P##7 << 16) * w7)); \
    ay += ((__uint_as_float(P##0 & 0xFFFF0000u) * w0 + __uint_as_float(P##1 & 0xFFFF0000u) * w1) + \
           (__uint_as_float(P##2 & 0xFFFF0000u) * w2 + __uint_as_float(P##3 & 0xFFFF0000u) * w3)) + \
          ((__uint_as_float(P##4 & 0xFFFF0000u) * w4 + __uint_as_float(P##5 & 0xFFFF0000u) * w5) + \
           (__uint_as_float(P##6 & 0xFFFF0000u) * w6 + __uint_as_float(P##7 & 0xFFFF0000u) * w7)); }

__global__ __launch_bounds__(256) void k_agg_ln(const __hip_bfloat16* __restrict__ g, const unsigned* __restrict__ pk,
                                                const int* __restrict__ bucketCnt, const int* __restrict__ cnt,
                                                const float* __restrict__ dinv, const float* __restrict__ bias,
                                                const float* __restrict__ gamma, const float* __restrict__ beta,
                                                float* __restrict__ out, int N) {
    __shared__ int sidx[SIDXSZ];    // ~10 KB: half-bucket's node-grouped src indices
    __shared__ int sscan[256];
    __shared__ int lofs[64];
    __shared__ int pvs[64];
    __shared__ int lcnt[64];
    int blk = blockIdx.x;
    int b = blk >> 1;               // 128-node bucket
    int half = blk & 1;             // which 64-node half
    int t = threadIdx.x;
    int ofs = b << CAPSH;
    int cntb = min(bucketCnt[b], CAP);
    // ---- phase 1: scan padded per-node counts (this half's 64 nodes) ----
    int nd = (b << 7) + (half << 6) + t;
    int v = (t < 64 && nd < N) ? cnt[nd] : 0;
    int pv = (v + 7) & ~7;          // pad to x8 (t>=64 contributes 0)
    sscan[t] = pv;
    __syncthreads();
    int val = pv;
    for (int off = 1; off < 256; off <<= 1) {
        int add = (t >= off) ? sscan[t - off] : 0;
        __syncthreads();
        val += add;
        sscan[t] = val;
        __syncthreads();
    }
    if (t < 64) {
        int base = val - pv;
        lofs[t] = base;
        pvs[t] = pv;
        lcnt[t] = 0;
        for (int i = v; i < pv; ++i) {          // pad slots -> dummy row N (dinv[N]=0)
            int sl = base + i;
            if (sl < SIDXSZ) sidx[sl] = N;
        }
    }
    __syncthreads();
    // ---- phase 2: scan bucket pk, keep own half, scatter into LDS sidx ----
    for (int e = t; e < cntb; e += 256) {
        unsigned u = pk[ofs + e];
        int d = u >> 20;                        // dstLocal in [0,128)
        if ((d >> 6) == half) {
            int dl = d & 63;
            int r = atomicAdd(&lcnt[dl], 1);
            int sl = lofs[dl] + r;
            if (sl < SIDXSZ) sidx[sl] = (int)(u & 0xFFFFFu);
        }
    }
    __syncthreads();
    // ---- phase 3: wave-per-node aggregate + LN + ReLU ----
    int lane = t & 63;
    int wv = t >> 6;
    const unsigned* g1 = (const unsigned*)g;    // u32 = channels {2*lane, 2*lane+1}
    float2 bi = ((const float2*)bias)[lane];
    float2 ga = ((const float2*)gamma)[lane];
    float2 be = ((const float2*)beta)[lane];
    for (int ii = 0; ii < 16; ++ii) {
        int nl = wv * 16 + ii;                  // [0,64)
        int node = (b << 7) + (half << 6) + nl;
        if (node >= N) break;                   // wave-uniform
        int startL = lofs[nl];
        int endL = startL + pvs[nl];
        float di = dinv[node];
        unsigned sv = g1[(size_t)node * 64 + lane];
        float ax = __uint_as_float(sv << 16) * di;          // self-loop: dinv[i]*h[i]
        float ay = __uint_as_float(sv & 0xFFFF0000u) * di;
        for (int eb = startL; eb < endL; eb += 64) {
            int myidx = (eb + lane < endL) ? sidx[eb + lane] : N;   // LDS, guarded
            float dlv = dinv[myidx];            // per-edge weight (L2-hot table; dinv[N]=0)
            int nb = min(64, endL - eb);        // multiple of 8
            if (nb >= 24) {                     // issue 24 before first use
                LOAD8(pa, 0)
                LOAD8(pb, 8)
                LOAD8(pc, 16)
                WACC8(pa, 0)
                WACC8(pb, 8)
                WACC8(pc, 16)
                for (int j = 24; j + 8 <= nb; j += 8) {   // deg>24 tail (~2% of nodes)
                    LOAD8(pd, j)
                    WACC8(pd, j)
                }
            } else if (nb == 16) {
                LOAD8(pe, 0)
                LOAD8(pf, 8)
                WACC8(pe, 0)
                WACC8(pf, 8)
            } else {
                LOAD8(pg, 0)
                WACC8(pg, 0)
            }
        }
        float vx = ax * di + bi.x;
        float vy = ay * di + bi.y;
        float sum = vx + vy, sq = vx * vx + vy * vy;
#pragma unroll
        for (int off = 32; off > 0; off >>= 1) {
            sum += __shfl_xor(sum, off, 64);
            sq += __shfl_xor(sq, off, 64);
        }
        float mu = sum * (1.0f / 128.0f);
        float var = sq * (1.0f / 128.0f) - mu * mu;
        float rstd = rsqrtf(var + LN_EPS);
        float o0 = fmaxf((vx - mu) * rstd * ga.x + be.x, 0.f);
        float o1 = fmaxf((vy - mu) * rstd * ga.y + be.y, 0.f);
        ((float2*)out)[(size_t)node * 64 + lane] = make_float2(o0, o1);
    }
}

extern "C" void kernel_launch(void* const* d_in, const int* in_sizes, int n_in,
                              void* d_out, int out_size, void* d_ws, size_t ws_size,
                              hipStream_t stream) {
    const float* x = (const float*)d_in[0];
    const int* ei = (const int*)d_in[1];
    const float* W = (const float*)d_in[2];
    const float* bias = (const float*)d_in[3];
    const float* gamma = (const float*)d_in[4];
    const float* beta = (const float*)d_in[5];
    float* out = (float*)d_out;

    int N = in_sizes[0] / 128;
    int E = in_sizes[1] / 2;
    int NBUCK = (N + 127) / 128;                 // 128-node buckets (782)

    char* p = (char*)d_ws;
    auto alloc = [&](size_t bytes) {
        char* r = p;
        p += (bytes + 255) & ~(size_t)255;
        return r;
    };
    int* bucketCnt = (int*)alloc(MAXBUCK * 4);
    int* cnt = (int*)alloc((size_t)N * 4);
    float* dinv = (float*)alloc((size_t)(N + 1) * 4);            // +1: dinv[N]=0 pad weight
    __hip_bfloat16* Wt = (__hip_bfloat16*)alloc(128 * 128 * 2);
    unsigned* pk = (unsigned*)alloc((size_t)NBUCK * CAP * 4);    // 12.8MB (ws: agg reads pk while writing d_out)
    __hip_bfloat16* gbuf = (__hip_bfloat16*)alloc((size_t)(N + 1) * 128 * 2);  // +1 dummy zero row

    int chunk = (E + NPBLK - 1) / NPBLK;         // 2778 <= 2816 LDS buffer
    int GB = (N + 127) / 128;

    k_init<<<64, 256, 0, stream>>>(W, Wt, bucketCnt, (unsigned*)(gbuf + (size_t)N * 128), dinv, N);
    k_part_gemm<<<NPBLK + GB, 256, 0, stream>>>(ei, bucketCnt, pk, E, chunk, x, Wt, gbuf, N);
    k_deg<<<NBUCK, 256, 0, stream>>>(pk, bucketCnt, cnt, dinv, N);
    k_agg_ln<<<NBUCK * 2, 256, 0, stream>>>(gbuf, pk, bucketCnt, cnt, dinv, bias, gamma, beta, out, N);
}